// Round 1
// baseline (462.999 us; speedup 1.0000x reference)
//
#include <hip/hip_runtime.h>
#include <cstdint>
#include <cstddef>

#define EMBED 1024
#define NHEAD 16
#define HD    64
#define BATCH 2
#define SEQ   2048
#define MROWS (BATCH*SEQ)   // 4096

typedef __bf16 bf16;
typedef __bf16 bf16x8 __attribute__((ext_vector_type(8)));
typedef float  f32x4  __attribute__((ext_vector_type(4)));

// ---------------- cast fp32 -> bf16, 8 elements/thread ----------------
__global__ void cast_kernel(const float* __restrict__ in, bf16* __restrict__ out, int n8) {
  int i = blockIdx.x * blockDim.x + threadIdx.x;
  if (i >= n8) return;
  const float4* p = (const float4*)in;
  float4 a = p[2*i], b = p[2*i+1];
  union { bf16 h[8]; uint4 u; } r;
  r.h[0] = (bf16)a.x; r.h[1] = (bf16)a.y; r.h[2] = (bf16)a.z; r.h[3] = (bf16)a.w;
  r.h[4] = (bf16)b.x; r.h[5] = (bf16)b.y; r.h[6] = (bf16)b.z; r.h[7] = (bf16)b.w;
  ((uint4*)out)[i] = r.u;
}

// ---------------- C = A @ B^T, bf16 in, fp32 accum --------------------
// A: [M][K] row-major bf16, Bmat: [N][K] row-major bf16.
// outb != null -> bf16 out = (acc + bias[col]) * scale
// else         -> fp32 out = (acc + bias[col]) * scale
#define BM 128
#define BN 128
#define BK 32
#define LDT 40   // LDS row stride (bf16 elems); 80B -> 2-way max conflicts

__global__ __launch_bounds__(256) void gemm_abt(
    const bf16* __restrict__ A, const bf16* __restrict__ Bmat,
    const float* __restrict__ bias, float scale,
    bf16* __restrict__ outb, float* __restrict__ outf, int Kdim, int Ndim)
{
  __shared__ bf16 Al[BM*LDT];
  __shared__ bf16 Bl[BN*LDT];
  const int tid  = threadIdx.x;
  const int lane = tid & 63;
  const int wid  = tid >> 6;
  const int quad = lane >> 4, l16 = lane & 15;
  const int wm = wid >> 1, wn = wid & 1;
  const int m0 = blockIdx.y * BM, n0 = blockIdx.x * BN;

  const int r0 = tid >> 2;            // rows 0..63
  const int r1 = r0 + 64;             // rows 64..127
  const int c0 = (tid & 3) * 8;       // k-offset within tile

  f32x4 acc[4][4] = {};

  for (int k0 = 0; k0 < Kdim; k0 += BK) {
    uint4 a0 = *(const uint4*)(A    + (size_t)(m0 + r0)*Kdim + k0 + c0);
    uint4 a1 = *(const uint4*)(A    + (size_t)(m0 + r1)*Kdim + k0 + c0);
    uint4 b0 = *(const uint4*)(Bmat + (size_t)(n0 + r0)*Kdim + k0 + c0);
    uint4 b1 = *(const uint4*)(Bmat + (size_t)(n0 + r1)*Kdim + k0 + c0);
    __syncthreads();
    *(uint4*)(Al + r0*LDT + c0) = a0;
    *(uint4*)(Al + r1*LDT + c0) = a1;
    *(uint4*)(Bl + r0*LDT + c0) = b0;
    *(uint4*)(Bl + r1*LDT + c0) = b1;
    __syncthreads();
    bf16x8 af[4], bg[4];
#pragma unroll
    for (int i = 0; i < 4; ++i) {
      af[i] = *(const bf16x8*)(Al + (wm*64 + i*16 + l16)*LDT + quad*8);
      bg[i] = *(const bf16x8*)(Bl + (wn*64 + i*16 + l16)*LDT + quad*8);
    }
#pragma unroll
    for (int i = 0; i < 4; ++i)
#pragma unroll
      for (int j = 0; j < 4; ++j)
        acc[i][j] = __builtin_amdgcn_mfma_f32_16x16x32_bf16(af[i], bg[j], acc[i][j], 0, 0, 0);
  }

#pragma unroll
  for (int i = 0; i < 4; ++i) {
#pragma unroll
    for (int j = 0; j < 4; ++j) {
      int col = n0 + wn*64 + j*16 + l16;
      float bv = bias[col];
#pragma unroll
      for (int r = 0; r < 4; ++r) {
        int row = m0 + wm*64 + i*16 + quad*4 + r;
        float v = (acc[i][j][r] + bv) * scale;
        if (outb) outb[(size_t)row*Ndim + col] = (bf16)v;
        else      outf[(size_t)row*Ndim + col] = v;
      }
    }
  }
}

// ---------------- flash attention with patch mask ---------------------
// block = (q-tile of 64 rows, head, batch); 4 waves, 16 q-rows each.
// Q pre-scaled by 1/8 at projection. Key tile = 32 keys.
__global__ __launch_bounds__(256) void attn_kernel(
    const bf16* __restrict__ Qp, const bf16* __restrict__ Kp, const bf16* __restrict__ Vp,
    const int* __restrict__ pmask, bf16* __restrict__ Ctx)
{
  __shared__ bf16 Kt[32*72];      // [key][dim], stride 72
  __shared__ bf16 Vt[64*40];      // [dim][key] (transposed), stride 40
  __shared__ bf16 Pl[4][16*40];   // per-wave P tile [qrow][key], stride 40

  const int qt = blockIdx.x, h = blockIdx.y, b = blockIdx.z;
  const int tid = threadIdx.x, lane = tid & 63, wid = tid >> 6;
  const int quad = lane >> 4, l16 = lane & 15;
  const int qrow0 = qt*64 + wid*16;

  const size_t qoff = (size_t)(b*SEQ + qrow0 + l16)*EMBED + h*HD;
  bf16x8 qf0 = *(const bf16x8*)(Qp + qoff + quad*8);
  bf16x8 qf1 = *(const bf16x8*)(Qp + qoff + 32 + quad*8);

  int qm[4];
#pragma unroll
  for (int r = 0; r < 4; ++r) qm[r] = pmask[b*SEQ + qrow0 + quad*4 + r];

  f32x4 o[4] = {};              // o[t]: dims t*16+l16, rows quad*4+reg
  float mrow[4], lrow[4];
#pragma unroll
  for (int r = 0; r < 4; ++r) { mrow[r] = -3e38f; lrow[r] = 0.f; }

  const int stg_key = tid >> 3, stg_c = (tid & 7) * 8;

  for (int kt = 0; kt < SEQ/32; ++kt) {
    __syncthreads();
    {
      const size_t base = (size_t)(b*SEQ + kt*32 + stg_key)*EMBED + h*HD + stg_c;
      uint4 kv = *(const uint4*)(Kp + base);
      *(uint4*)(Kt + stg_key*72 + stg_c) = kv;
      union { uint4 u; bf16 hh[8]; } vv;
      vv.u = *(const uint4*)(Vp + base);
#pragma unroll
      for (int i2 = 0; i2 < 8; ++i2) Vt[(stg_c + i2)*40 + stg_key] = vv.hh[i2];
    }
    __syncthreads();

    const int km0 = pmask[b*SEQ + kt*32 + l16];
    const int km1 = pmask[b*SEQ + kt*32 + 16 + l16];

    f32x4 s0 = {}, s1 = {};
    {
      bf16x8 k00 = *(const bf16x8*)(Kt + l16*72 + quad*8);
      bf16x8 k01 = *(const bf16x8*)(Kt + l16*72 + 32 + quad*8);
      s0 = __builtin_amdgcn_mfma_f32_16x16x32_bf16(qf0, k00, s0, 0, 0, 0);
      s0 = __builtin_amdgcn_mfma_f32_16x16x32_bf16(qf1, k01, s0, 0, 0, 0);
      bf16x8 k10 = *(const bf16x8*)(Kt + (16 + l16)*72 + quad*8);
      bf16x8 k11 = *(const bf16x8*)(Kt + (16 + l16)*72 + 32 + quad*8);
      s1 = __builtin_amdgcn_mfma_f32_16x16x32_bf16(qf0, k10, s1, 0, 0, 0);
      s1 = __builtin_amdgcn_mfma_f32_16x16x32_bf16(qf1, k11, s1, 0, 0, 0);
    }

    float alpha[4];
#pragma unroll
    for (int r = 0; r < 4; ++r) {
      float v0 = km0 ? s0[r] : -3e38f;
      float v1 = km1 ? s1[r] : -3e38f;
      float tm = fmaxf(v0, v1);
#pragma unroll
      for (int off2 = 1; off2 < 16; off2 <<= 1) tm = fmaxf(tm, __shfl_xor(tm, off2));
      float nm = fmaxf(mrow[r], tm);
      float al = __expf(mrow[r] - nm);
      float p0 = km0 ? __expf(s0[r] - nm) : 0.f;
      float p1 = km1 ? __expf(s1[r] - nm) : 0.f;
      float rs = p0 + p1;
#pragma unroll
      for (int off2 = 1; off2 < 16; off2 <<= 1) rs += __shfl_xor(rs, off2);
      lrow[r] = lrow[r]*al + rs;
      mrow[r] = nm;
      alpha[r] = al;
      Pl[wid][(quad*4 + r)*40 + l16]      = (bf16)p0;
      Pl[wid][(quad*4 + r)*40 + 16 + l16] = (bf16)p1;
    }
#pragma unroll
    for (int t = 0; t < 4; ++t)
#pragma unroll
      for (int r = 0; r < 4; ++r) o[t][r] *= alpha[r];

    __syncthreads();   // also orders Pl writes -> reads

    bf16x8 pf = *(const bf16x8*)(&Pl[wid][l16*40 + quad*8]);
#pragma unroll
    for (int t = 0; t < 4; ++t) {
      bf16x8 vf = *(const bf16x8*)(Vt + (t*16 + l16)*40 + quad*8);
      o[t] = __builtin_amdgcn_mfma_f32_16x16x32_bf16(pf, vf, o[t], 0, 0, 0);
    }
  }

#pragma unroll
  for (int t = 0; t < 4; ++t) {
#pragma unroll
    for (int r = 0; r < 4; ++r) {
      float v = (qm[r] && lrow[r] > 0.f) ? (o[t][r] / lrow[r]) : 0.f;
      int row = b*SEQ + qrow0 + quad*4 + r;
      Ctx[(size_t)row*EMBED + h*HD + t*16 + l16] = (bf16)v;
    }
  }
}

// ----------------------------------------------------------------------
extern "C" void kernel_launch(void* const* d_in, const int* in_sizes, int n_in,
                              void* d_out, int out_size, void* d_ws, size_t ws_size,
                              hipStream_t stream)
{
  const float* query = (const float*)d_in[0];
  const float* key   = (const float*)d_in[1];
  const float* value = (const float*)d_in[2];
  const int*   pm    = (const int*)d_in[3];
  const float* Wq = (const float*)d_in[4];
  const float* bq = (const float*)d_in[5];
  const float* Wk = (const float*)d_in[6];
  const float* bk = (const float*)d_in[7];
  const float* Wv = (const float*)d_in[8];
  const float* bv = (const float*)d_in[9];
  const float* Wo = (const float*)d_in[10];
  const float* bo = (const float*)d_in[11];
  float* out = (float*)d_out;

  const size_t SZ_X = (size_t)MROWS * EMBED;   // 4M elems
  const size_t SZ_W = (size_t)EMBED * EMBED;   // 1M elems

  bf16* p   = (bf16*)d_ws;
  bf16* Xq  = p; p += SZ_X;
  bf16* Xk  = p; p += SZ_X;
  bf16* Xv  = p; p += SZ_X;
  bf16* Wqb = p; p += SZ_W;
  bf16* Wkb = p; p += SZ_W;
  bf16* Wvb = p; p += SZ_W;
  bf16* Wob = p; p += SZ_W;
  bf16* Qp  = p; p += SZ_X;
  bf16* Kp  = p; p += SZ_X;
  bf16* Vp  = p; p += SZ_X;
  bf16* Ctx = p; p += SZ_X;

  cast_kernel<<<(int)(SZ_X/8/256), 256, 0, stream>>>(query, Xq, (int)(SZ_X/8));
  cast_kernel<<<(int)(SZ_X/8/256), 256, 0, stream>>>(key,   Xk, (int)(SZ_X/8));
  cast_kernel<<<(int)(SZ_X/8/256), 256, 0, stream>>>(value, Xv, (int)(SZ_X/8));
  cast_kernel<<<(int)(SZ_W/8/256), 256, 0, stream>>>(Wq, Wqb, (int)(SZ_W/8));
  cast_kernel<<<(int)(SZ_W/8/256), 256, 0, stream>>>(Wk, Wkb, (int)(SZ_W/8));
  cast_kernel<<<(int)(SZ_W/8/256), 256, 0, stream>>>(Wv, Wvb, (int)(SZ_W/8));
  cast_kernel<<<(int)(SZ_W/8/256), 256, 0, stream>>>(Wo, Wob, (int)(SZ_W/8));

  dim3 gg(EMBED/BN, MROWS/BM);   // (8, 32)
  gemm_abt<<<gg, 256, 0, stream>>>(Xq, Wqb, bq, 0.125f, Qp, nullptr, EMBED, EMBED);
  gemm_abt<<<gg, 256, 0, stream>>>(Xk, Wkb, bk, 1.0f,   Kp, nullptr, EMBED, EMBED);
  gemm_abt<<<gg, 256, 0, stream>>>(Xv, Wvb, bv, 1.0f,   Vp, nullptr, EMBED, EMBED);

  dim3 ga(SEQ/64, NHEAD, BATCH); // (32, 16, 2)
  attn_kernel<<<ga, 256, 0, stream>>>(Qp, Kp, Vp, pm, Ctx);

  gemm_abt<<<gg, 256, 0, stream>>>(Ctx, Wob, bo, 1.0f, nullptr, out, EMBED, EMBED);
}

// Round 2
// 317.683 us; speedup vs baseline: 1.4574x; 1.4574x over previous
//
#include <hip/hip_runtime.h>
#include <cstdint>
#include <cstddef>

#define EMBED 1024
#define NHEAD 16
#define HD    64
#define BATCH 2
#define SEQ   2048
#define MROWS (BATCH*SEQ)   // 4096

typedef __bf16 bf16;
typedef __bf16 bf16x8 __attribute__((ext_vector_type(8)));
typedef float  f32x4  __attribute__((ext_vector_type(4)));

#if __has_builtin(__builtin_amdgcn_exp2f)
#define EXP2(x) __builtin_amdgcn_exp2f(x)
#else
#define EXP2(x) exp2f(x)
#endif

// ---------------- cast fp32 -> bf16, 8 elements/thread ----------------
__global__ void cast_kernel(const float* __restrict__ in, bf16* __restrict__ out, int n8) {
  int i = blockIdx.x * blockDim.x + threadIdx.x;
  if (i >= n8) return;
  const float4* p = (const float4*)in;
  float4 a = p[2*i], b = p[2*i+1];
  union { bf16 h[8]; uint4 u; } r;
  r.h[0] = (bf16)a.x; r.h[1] = (bf16)a.y; r.h[2] = (bf16)a.z; r.h[3] = (bf16)a.w;
  r.h[4] = (bf16)b.x; r.h[5] = (bf16)b.y; r.h[6] = (bf16)b.z; r.h[7] = (bf16)b.w;
  ((uint4*)out)[i] = r.u;
}

// ---------------- C = A @ B^T, bf16 in, fp32 accum --------------------
// A: [M][K] row-major bf16, Bmat: [N][K] row-major bf16.
// outT != null -> bf16 out in transposed [b][h][d][s] layout (for V)
// outb != null -> bf16 out = (acc + bias[col]) * scale
// else         -> fp32 out = (acc + bias[col]) * scale
#define BM 128
#define BN 128
#define BK 32
#define LDT 40   // LDS row stride (bf16 elems); 80B -> 2-way max conflicts

__global__ __launch_bounds__(256) void gemm_abt(
    const bf16* __restrict__ A, const bf16* __restrict__ Bmat,
    const float* __restrict__ bias, float scale,
    bf16* __restrict__ outb, float* __restrict__ outf, bf16* __restrict__ outT,
    int Kdim, int Ndim)
{
  __shared__ bf16 Al[BM*LDT];
  __shared__ bf16 Bl[BN*LDT];
  const int tid  = threadIdx.x;
  const int lane = tid & 63;
  const int wid  = tid >> 6;
  const int quad = lane >> 4, l16 = lane & 15;
  const int wm = wid >> 1, wn = wid & 1;
  const int m0 = blockIdx.y * BM, n0 = blockIdx.x * BN;

  const int r0 = tid >> 2;            // rows 0..63
  const int r1 = r0 + 64;             // rows 64..127
  const int c0 = (tid & 3) * 8;       // k-offset within tile

  f32x4 acc[4][4] = {};

  for (int k0 = 0; k0 < Kdim; k0 += BK) {
    uint4 a0 = *(const uint4*)(A    + (size_t)(m0 + r0)*Kdim + k0 + c0);
    uint4 a1 = *(const uint4*)(A    + (size_t)(m0 + r1)*Kdim + k0 + c0);
    uint4 b0 = *(const uint4*)(Bmat + (size_t)(n0 + r0)*Kdim + k0 + c0);
    uint4 b1 = *(const uint4*)(Bmat + (size_t)(n0 + r1)*Kdim + k0 + c0);
    __syncthreads();
    *(uint4*)(Al + r0*LDT + c0) = a0;
    *(uint4*)(Al + r1*LDT + c0) = a1;
    *(uint4*)(Bl + r0*LDT + c0) = b0;
    *(uint4*)(Bl + r1*LDT + c0) = b1;
    __syncthreads();
    bf16x8 af[4], bg[4];
#pragma unroll
    for (int i = 0; i < 4; ++i) {
      af[i] = *(const bf16x8*)(Al + (wm*64 + i*16 + l16)*LDT + quad*8);
      bg[i] = *(const bf16x8*)(Bl + (wn*64 + i*16 + l16)*LDT + quad*8);
    }
#pragma unroll
    for (int i = 0; i < 4; ++i)
#pragma unroll
      for (int j = 0; j < 4; ++j)
        acc[i][j] = __builtin_amdgcn_mfma_f32_16x16x32_bf16(af[i], bg[j], acc[i][j], 0, 0, 0);
  }

#pragma unroll
  for (int i = 0; i < 4; ++i) {
#pragma unroll
    for (int j = 0; j < 4; ++j) {
      int col = n0 + wn*64 + j*16 + l16;
      float bv = bias[col];
      if (outT) {
        // transposed V layout: VT[b][h][d][s], 4 consecutive tokens packed
        int row0 = m0 + wm*64 + i*16 + quad*4;
        int bb = row0 >> 11, ss = row0 & (SEQ-1);
        int hh = col >> 6, dd = col & (HD-1);
        union { bf16 h4[4]; uint2 u; } pk;
#pragma unroll
        for (int r = 0; r < 4; ++r) pk.h4[r] = (bf16)((acc[i][j][r] + bv) * scale);
        *(uint2*)(outT + (((size_t)bb*NHEAD + hh)*HD + dd)*SEQ + ss) = pk.u;
      } else {
#pragma unroll
        for (int r = 0; r < 4; ++r) {
          int row = m0 + wm*64 + i*16 + quad*4 + r;
          float v = (acc[i][j][r] + bv) * scale;
          if (outb) outb[(size_t)row*Ndim + col] = (bf16)v;
          else      outf[(size_t)row*Ndim + col] = v;
        }
      }
    }
  }
}

// ---------------- flash attention, no-max-sub softmax -----------------
// block = (64 q-rows, head, batch); 4 waves x 16 q-rows; 64-key tiles.
// Q pre-scaled by log2(e)/8 at projection -> p = exp2(s).
// Row-sums l accumulated via MFMA against an all-ones B fragment.
#define KST 72   // LDS row stride for K / V^T / P tiles (144 B, 16B-aligned)

__global__ __launch_bounds__(256, 4) void attn_kernel(
    const bf16* __restrict__ Qp, const bf16* __restrict__ Kp, const bf16* __restrict__ VT,
    const int* __restrict__ pmask, bf16* __restrict__ Ctx)
{
  __shared__ bf16 Kt[64*KST];     // [key][dim]
  __shared__ bf16 Vt[64*KST];     // [dim][key]  (from global V^T)
  __shared__ bf16 Pl[4][16*KST];  // per-wave P tile [qrow][key]

  const int qt = blockIdx.x, h = blockIdx.y, b = blockIdx.z;
  const int tid = threadIdx.x, lane = tid & 63, wid = tid >> 6;
  const int quad = lane >> 4, l16 = lane & 15;
  const int qrow0 = qt*64 + wid*16;

  const size_t qoff = (size_t)(b*SEQ + qrow0 + l16)*EMBED + h*HD;
  bf16x8 qf0 = *(const bf16x8*)(Qp + qoff + quad*8);
  bf16x8 qf1 = *(const bf16x8*)(Qp + qoff + 32 + quad*8);

  int qm[4];
#pragma unroll
  for (int r = 0; r < 4; ++r) qm[r] = pmask[b*SEQ + qrow0 + quad*4 + r];

  bf16 onev = (bf16)1.0f;
  bf16x8 ones = {onev, onev, onev, onev, onev, onev, onev, onev};

  f32x4 o[4] = {};     // o[t]: dim t*16+l16, rows quad*4+r
  f32x4 lacc = {};     // row sums (all 16 cols identical)

  const int c0 = tid >> 3;        // 0..31
  const int c1 = (tid & 7) * 8;

  const bf16* Kg  = Kp + ((size_t)b*SEQ)*EMBED + h*HD;
  const bf16* VTg = VT + ((size_t)(b*NHEAD + h)*HD)*SEQ;

  for (int kt = 0; kt < SEQ/64; ++kt) {
    // issue staging loads before the barrier
    const size_t kbase = (size_t)(kt*64 + c0)*EMBED + c1;
    uint4 k0 = *(const uint4*)(Kg + kbase);
    uint4 k1 = *(const uint4*)(Kg + kbase + (size_t)32*EMBED);
    const bf16* vg = VTg + (size_t)c0*SEQ + kt*64 + c1;
    uint4 v0 = *(const uint4*)(vg);
    uint4 v1 = *(const uint4*)(vg + (size_t)32*SEQ);

    __syncthreads();   // prev tile's reads of Kt/Vt done
    *(uint4*)(Kt + c0*KST + c1)      = k0;
    *(uint4*)(Kt + (c0+32)*KST + c1) = k1;
    *(uint4*)(Vt + c0*KST + c1)      = v0;
    *(uint4*)(Vt + (c0+32)*KST + c1) = v1;
    __syncthreads();   // staging visible

    // QK^T + exp2 + P store, per 16-key group
#pragma unroll
    for (int g = 0; g < 4; ++g) {
      bf16x8 kfa = *(const bf16x8*)(Kt + (g*16 + l16)*KST + quad*8);
      bf16x8 kfb = *(const bf16x8*)(Kt + (g*16 + l16)*KST + 32 + quad*8);
      f32x4 sg = {};
      sg = __builtin_amdgcn_mfma_f32_16x16x32_bf16(qf0, kfa, sg, 0, 0, 0);
      sg = __builtin_amdgcn_mfma_f32_16x16x32_bf16(qf1, kfb, sg, 0, 0, 0);
      int km = pmask[b*SEQ + kt*64 + g*16 + l16];
#pragma unroll
      for (int r = 0; r < 4; ++r) {
        float sv = km ? sg[r] : -__builtin_inff();
        Pl[wid][(quad*4 + r)*KST + g*16 + l16] = (bf16)EXP2(sv);
      }
    }

    __syncthreads();   // P writes visible (cross-lane within wave)

    bf16x8 pf0 = *(const bf16x8*)(&Pl[wid][l16*KST + quad*8]);
    bf16x8 pf1 = *(const bf16x8*)(&Pl[wid][l16*KST + 32 + quad*8]);
    lacc = __builtin_amdgcn_mfma_f32_16x16x32_bf16(pf0, ones, lacc, 0, 0, 0);
    lacc = __builtin_amdgcn_mfma_f32_16x16x32_bf16(pf1, ones, lacc, 0, 0, 0);
#pragma unroll
    for (int t = 0; t < 4; ++t) {
      bf16x8 vf0 = *(const bf16x8*)(Vt + (t*16 + l16)*KST + quad*8);
      bf16x8 vf1 = *(const bf16x8*)(Vt + (t*16 + l16)*KST + 32 + quad*8);
      o[t] = __builtin_amdgcn_mfma_f32_16x16x32_bf16(pf0, vf0, o[t], 0, 0, 0);
      o[t] = __builtin_amdgcn_mfma_f32_16x16x32_bf16(pf1, vf1, o[t], 0, 0, 0);
    }
  }

  float inv[4];
#pragma unroll
  for (int r = 0; r < 4; ++r)
    inv[r] = (qm[r] && lacc[r] > 0.f) ? 1.0f / lacc[r] : 0.0f;

#pragma unroll
  for (int t = 0; t < 4; ++t) {
#pragma unroll
    for (int r = 0; r < 4; ++r) {
      int row = b*SEQ + qrow0 + quad*4 + r;
      Ctx[(size_t)row*EMBED + h*HD + t*16 + l16] = (bf16)(o[t][r] * inv[r]);
    }
  }
}

// ----------------------------------------------------------------------
extern "C" void kernel_launch(void* const* d_in, const int* in_sizes, int n_in,
                              void* d_out, int out_size, void* d_ws, size_t ws_size,
                              hipStream_t stream)
{
  const float* query = (const float*)d_in[0];
  const float* key   = (const float*)d_in[1];
  const float* value = (const float*)d_in[2];
  const int*   pm    = (const int*)d_in[3];
  const float* Wq = (const float*)d_in[4];
  const float* bq = (const float*)d_in[5];
  const float* Wk = (const float*)d_in[6];
  const float* bk = (const float*)d_in[7];
  const float* Wv = (const float*)d_in[8];
  const float* bv = (const float*)d_in[9];
  const float* Wo = (const float*)d_in[10];
  const float* bo = (const float*)d_in[11];
  float* out = (float*)d_out;

  const size_t SZ_X = (size_t)MROWS * EMBED;   // 4M elems
  const size_t SZ_W = (size_t)EMBED * EMBED;   // 1M elems

  bf16* p   = (bf16*)d_ws;
  bf16* Xq  = p; p += SZ_X;
  bf16* Xk  = p; p += SZ_X;
  bf16* Xv  = p; p += SZ_X;
  bf16* Wqb = p; p += SZ_W;
  bf16* Wkb = p; p += SZ_W;
  bf16* Wvb = p; p += SZ_W;
  bf16* Wob = p; p += SZ_W;
  bf16* Qp  = p; p += SZ_X;
  bf16* Kp  = p; p += SZ_X;
  bf16* VTg = p; p += SZ_X;   // V^T: [b][h][d][s]
  bf16* Ctx = p; p += SZ_X;

  cast_kernel<<<(int)(SZ_X/8/256), 256, 0, stream>>>(query, Xq, (int)(SZ_X/8));
  cast_kernel<<<(int)(SZ_X/8/256), 256, 0, stream>>>(key,   Xk, (int)(SZ_X/8));
  cast_kernel<<<(int)(SZ_X/8/256), 256, 0, stream>>>(value, Xv, (int)(SZ_X/8));
  cast_kernel<<<(int)(SZ_W/8/256), 256, 0, stream>>>(Wq, Wqb, (int)(SZ_W/8));
  cast_kernel<<<(int)(SZ_W/8/256), 256, 0, stream>>>(Wk, Wkb, (int)(SZ_W/8));
  cast_kernel<<<(int)(SZ_W/8/256), 256, 0, stream>>>(Wv, Wvb, (int)(SZ_W/8));
  cast_kernel<<<(int)(SZ_W/8/256), 256, 0, stream>>>(Wo, Wob, (int)(SZ_W/8));

  dim3 gg(EMBED/BN, MROWS/BM);   // (8, 32)
  // Q pre-scaled by log2(e)/8 so attention can use exp2 directly
  gemm_abt<<<gg, 256, 0, stream>>>(Xq, Wqb, bq, 0.1803368801111137f, Qp, nullptr, nullptr, EMBED, EMBED);
  gemm_abt<<<gg, 256, 0, stream>>>(Xk, Wkb, bk, 1.0f, Kp, nullptr, nullptr, EMBED, EMBED);
  gemm_abt<<<gg, 256, 0, stream>>>(Xv, Wvb, bv, 1.0f, nullptr, nullptr, VTg, EMBED, EMBED);

  dim3 ga(SEQ/64, NHEAD, BATCH); // (32, 16, 2)
  attn_kernel<<<ga, 256, 0, stream>>>(Qp, Kp, VTg, pm, Ctx);

  gemm_abt<<<gg, 256, 0, stream>>>(Ctx, Wob, bo, 1.0f, nullptr, out, nullptr, EMBED, EMBED);
}

// Round 4
// 256.017 us; speedup vs baseline: 1.8085x; 1.2409x over previous
//
#include <hip/hip_runtime.h>
#include <cstdint>
#include <cstddef>

#define EMBED 1024
#define NHEAD 16
#define HD    64
#define BATCH 2
#define SEQ   2048
#define MROWS (BATCH*SEQ)   // 4096
#define QSCALE 0.1803368801111137f   // log2(e)/8

typedef __bf16 bf16;
typedef __bf16 bf16x8 __attribute__((ext_vector_type(8)));
typedef float  f32x4  __attribute__((ext_vector_type(4)));
typedef unsigned int u32;

#if __has_builtin(__builtin_amdgcn_exp2f)
#define EXP2(x) __builtin_amdgcn_exp2f(x)
#else
#define EXP2(x) exp2f(x)
#endif

typedef const u32 __attribute__((address_space(1)))* gp_t;
typedef u32 __attribute__((address_space(3)))* lp_t;

// async global->LDS, 16B/lane; LDS dest = wave-uniform base + lane*16
__device__ __forceinline__ void g2l16(const void* g, void* l) {
  __builtin_amdgcn_global_load_lds((gp_t)(uintptr_t)g, (lp_t)(u32)(uintptr_t)l, 16, 0, 0);
}

#define MFMA(a, b, c) __builtin_amdgcn_mfma_f32_16x16x32_bf16((a), (b), (c), 0, 0, 0)

// ---------------- fused casts fp32 -> bf16 ----------------------------
__global__ void cast_multi(const float* __restrict__ p0, const float* __restrict__ p1,
                           const float* __restrict__ p2, const float* __restrict__ p3,
                           bf16* o0, bf16* o1, bf16* o2, bf16* o3, int n8) {
  int z = blockIdx.y;
  const float* in = z==0?p0 : z==1?p1 : z==2?p2 : p3;
  bf16*       out = z==0?o0 : z==1?o1 : z==2?o2 : o3;
  int i = blockIdx.x * blockDim.x + threadIdx.x;
  if (i >= n8) return;
  const float4* p = (const float4*)in;
  float4 a = p[2*i], b = p[2*i+1];
  union { bf16 h[8]; uint4 u; } r;
  r.h[0] = (bf16)a.x; r.h[1] = (bf16)a.y; r.h[2] = (bf16)a.z; r.h[3] = (bf16)a.w;
  r.h[4] = (bf16)b.x; r.h[5] = (bf16)b.y; r.h[6] = (bf16)b.z; r.h[7] = (bf16)b.w;
  ((uint4*)out)[i] = r.u;
}

// ---------------- GEMM core: C = A @ W^T ------------------------------
// 128x128 tile, BK=32, double-buffered LDS via global_load_lds dwordx4.
// LDS layout unpadded stride-32, chunk-swizzled: phys16B = logical ^ ((row>>1)&3).
#define BM 128
#define BN 128
#define BK 32
#define NKI (EMBED/BK)   // 32

__device__ __forceinline__ void gemm_core(
    const bf16* __restrict__ A, const bf16* __restrict__ W,
    bf16* Al, bf16* Bl, f32x4 (&acc)[4][4])
{
  const int tid  = threadIdx.x;
  const int lane = tid & 63, wid = tid >> 6;
  const int quad = lane >> 4, l16 = lane & 15;
  const int wm = wid >> 1, wn = wid & 1;
  const int m0 = blockIdx.y * BM, n0 = blockIdx.x * BN;

  const int R = tid >> 2, Cc = tid & 3;
  const int gcol = (Cc ^ ((R >> 1) & 3)) * 8;          // swizzled source column
  const bf16* Ag = A + (size_t)(m0 + R) * EMBED + gcol;
  const bf16* Bg = W + (size_t)(n0 + R) * EMBED + gcol;
  bf16* AlW = Al + wid * 512;                          // wave's 1KB chunk
  bf16* BlW = Bl + wid * 512;

  // prologue: stage k-tile 0 into buffer 0
  g2l16(Ag, AlW);                      g2l16(Ag + (size_t)64*EMBED, AlW + 2048);
  g2l16(Bg, BlW);                      g2l16(Bg + (size_t)64*EMBED, BlW + 2048);
  __syncthreads();

  for (int ki = 0; ki < NKI; ++ki) {
    const int cur = ki & 1;
    if (ki + 1 < NKI) {                // async prefetch next k-tile into other buffer
      const int nb = cur ^ 1;
      const int k0 = (ki + 1) * BK;
      g2l16(Ag + k0, AlW + nb*4096);
      g2l16(Ag + (size_t)64*EMBED + k0, AlW + nb*4096 + 2048);
      g2l16(Bg + k0, BlW + nb*4096);
      g2l16(Bg + (size_t)64*EMBED + k0, BlW + nb*4096 + 2048);
    }
    const bf16* Ac = Al + cur*4096;
    const bf16* Bc = Bl + cur*4096;
    bf16x8 af[4], bg[4];
#pragma unroll
    for (int i = 0; i < 4; ++i) {
      int ra = wm*64 + i*16 + l16;
      af[i] = *(const bf16x8*)(Ac + ra*32 + ((quad ^ ((ra>>1)&3))*8));
      int rb = wn*64 + i*16 + l16;
      bg[i] = *(const bf16x8*)(Bc + rb*32 + ((quad ^ ((rb>>1)&3))*8));
    }
#pragma unroll
    for (int i = 0; i < 4; ++i)
#pragma unroll
      for (int j = 0; j < 4; ++j)
        acc[i][j] = MFMA(af[i], bg[j], acc[i][j]);
    __syncthreads();                   // drains prefetch (vmcnt) + compute done
  }
}

// QKV fused: blockIdx.z selects {Q,K,V}. Q scaled by log2(e)/8.
// V written transposed: VT[b][h][d][s].
__global__ __launch_bounds__(256) void qkv_kernel(
    const bf16* __restrict__ Xq, const bf16* __restrict__ Xk, const bf16* __restrict__ Xv,
    const bf16* __restrict__ Wq, const bf16* __restrict__ Wk, const bf16* __restrict__ Wv,
    const float* __restrict__ bq, const float* __restrict__ bk, const float* __restrict__ bv,
    bf16* __restrict__ Qp, bf16* __restrict__ Kp, bf16* __restrict__ VTg)
{
  __shared__ bf16 Al[2*BM*BK];
  __shared__ bf16 Bl[2*BN*BK];
  const int z = blockIdx.z;
  const bf16* A = z==0 ? Xq : z==1 ? Xk : Xv;
  const bf16* W = z==0 ? Wq : z==1 ? Wk : Wv;
  const float* bias = z==0 ? bq : z==1 ? bk : bv;
  const float scale = (z==0) ? QSCALE : 1.0f;

  f32x4 acc[4][4] = {};
  gemm_core(A, W, Al, Bl, acc);

  const int lane = threadIdx.x & 63, wid = threadIdx.x >> 6;
  const int quad = lane >> 4, l16 = lane & 15;
  const int wm = wid >> 1, wn = wid & 1;
  const int m0 = blockIdx.y * BM, n0 = blockIdx.x * BN;

#pragma unroll
  for (int i = 0; i < 4; ++i) {
#pragma unroll
    for (int j = 0; j < 4; ++j) {
      int col = n0 + wn*64 + j*16 + l16;
      float bv2 = bias[col];
      if (z < 2) {
        bf16* outp = (z == 0) ? Qp : Kp;
#pragma unroll
        for (int r = 0; r < 4; ++r) {
          int row = m0 + wm*64 + i*16 + quad*4 + r;
          outp[(size_t)row*EMBED + col] = (bf16)((acc[i][j][r] + bv2) * scale);
        }
      } else {
        int row0 = m0 + wm*64 + i*16 + quad*4;
        int bb = row0 >> 11, ss = row0 & (SEQ-1);
        int hh = col >> 6, dd = col & (HD-1);
        union { bf16 h4[4]; uint2 u; } pk;
#pragma unroll
        for (int r = 0; r < 4; ++r) pk.h4[r] = (bf16)(acc[i][j][r] + bv2);
        *(uint2*)(VTg + (((size_t)bb*NHEAD + hh)*HD + dd)*SEQ + ss) = pk.u;
      }
    }
  }
}

// O-projection: fp32 out
__global__ __launch_bounds__(256) void oproj_kernel(
    const bf16* __restrict__ Ctx, const bf16* __restrict__ Wo,
    const float* __restrict__ bo, float* __restrict__ out)
{
  __shared__ bf16 Al[2*BM*BK];
  __shared__ bf16 Bl[2*BN*BK];
  f32x4 acc[4][4] = {};
  gemm_core(Ctx, Wo, Al, Bl, acc);

  const int lane = threadIdx.x & 63, wid = threadIdx.x >> 6;
  const int quad = lane >> 4, l16 = lane & 15;
  const int wm = wid >> 1, wn = wid & 1;
  const int m0 = blockIdx.y * BM, n0 = blockIdx.x * BN;
#pragma unroll
  for (int i = 0; i < 4; ++i)
#pragma unroll
    for (int j = 0; j < 4; ++j) {
      int col = n0 + wn*64 + j*16 + l16;
      float bv = bo[col];
#pragma unroll
      for (int r = 0; r < 4; ++r) {
        int row = m0 + wm*64 + i*16 + quad*4 + r;
        out[(size_t)row*EMBED + col] = (acc[i][j][r] + bv);
      }
    }
}

// ---------------- flash attention, no-max softmax ---------------------
// 64 q-rows/block, 4 waves x 16 rows; 64-key tiles; double-buffered K/V
// staged via global_load_lds (unpadded 64-elem rows, chunk-swizzled
// phys16B = logical ^ (row&7)); one barrier per tile; P is wave-private.
#define NT  (SEQ/64)
#define PST 72   // P row stride: 64 keys + 8 pad (round-2-verified); MUST be >= 64

__global__ __launch_bounds__(256, 3) void attn_kernel(
    const bf16* __restrict__ Qp, const bf16* __restrict__ Kp, const bf16* __restrict__ VT,
    const int* __restrict__ pmask, bf16* __restrict__ Ctx)
{
  __shared__ bf16 Kt[2][64*64];
  __shared__ bf16 Vt[2][64*64];
  __shared__ bf16 Pl[4][16*PST];

  const int qt = blockIdx.x, h = blockIdx.y, b = blockIdx.z;
  const int tid = threadIdx.x, lane = tid & 63, wid = tid >> 6;
  const int quad = lane >> 4, l16 = lane & 15;
  const int qrow0 = qt*64 + wid*16;

  const size_t qoff = (size_t)(b*SEQ + qrow0 + l16)*EMBED + h*HD;
  bf16x8 qf0 = *(const bf16x8*)(Qp + qoff + quad*8);
  bf16x8 qf1 = *(const bf16x8*)(Qp + qoff + 32 + quad*8);

  int qm[4];
#pragma unroll
  for (int r = 0; r < 4; ++r) qm[r] = pmask[b*SEQ + qrow0 + quad*4 + r];

  bf16 onev = (bf16)1.0f;
  bf16x8 ones = {onev, onev, onev, onev, onev, onev, onev, onev};

  const bf16* Kg  = Kp + (size_t)b*SEQ*EMBED + h*HD;
  const bf16* VTg = VT + (size_t)(b*NHEAD + h)*HD*SEQ;

  const int R = tid >> 3;                 // 0..31 (key idx for K, dim for V)
  const int Cc = tid & 7;
  const int scol = (Cc ^ (R & 7)) * 8;    // swizzled source column

  f32x4 o[4] = {};
  f32x4 lacc = {};

#define STAGE(kt, buf) do {                                              \
    const bf16* kg = Kg + (size_t)((kt)*64 + R)*EMBED + scol;            \
    const bf16* vg = VTg + (size_t)R*SEQ + (kt)*64 + scol;               \
    bf16* kl = &Kt[buf][0] + wid*512;                                    \
    bf16* vl = &Vt[buf][0] + wid*512;                                    \
    g2l16(kg, kl);  g2l16(kg + (size_t)32*EMBED, kl + 2048);             \
    g2l16(vg, vl);  g2l16(vg + (size_t)32*SEQ,   vl + 2048);             \
  } while (0)

  STAGE(0, 0);
  __syncthreads();

  for (int kt = 0; kt < NT; ++kt) {
    const int cur = kt & 1;
    if (kt + 1 < NT) STAGE(kt + 1, cur ^ 1);   // async, lands by next barrier
    const bf16* Kc = &Kt[cur][0];
    const bf16* Vc = &Vt[cur][0];

#pragma unroll
    for (int g = 0; g < 4; ++g) {
      int ra = g*16 + l16, sa = ra & 7;
      bf16x8 kfa = *(const bf16x8*)(Kc + ra*64 + ((quad     ^ sa)*8));
      bf16x8 kfb = *(const bf16x8*)(Kc + ra*64 + (((quad+4) ^ sa)*8));
      f32x4 sg = {};
      sg = MFMA(qf0, kfa, sg);
      sg = MFMA(qf1, kfb, sg);
      int km = pmask[b*SEQ + kt*64 + g*16 + l16];
#pragma unroll
      for (int r = 0; r < 4; ++r) {
        float sv = km ? sg[r] : -__builtin_inff();
        Pl[wid][(quad*4 + r)*PST + g*16 + l16] = (bf16)EXP2(sv);
      }
    }

    // wave-private P: same-wave DS ordering + compiler lgkm wait, no barrier
    bf16x8 pf0 = *(const bf16x8*)(&Pl[wid][l16*PST + quad*8]);
    bf16x8 pf1 = *(const bf16x8*)(&Pl[wid][l16*PST + 32 + quad*8]);
    lacc = MFMA(pf0, ones, lacc);
    lacc = MFMA(pf1, ones, lacc);
#pragma unroll
    for (int t = 0; t < 4; ++t) {
      int rd = t*16 + l16, sd = rd & 7;
      bf16x8 vf0 = *(const bf16x8*)(Vc + rd*64 + ((quad     ^ sd)*8));
      bf16x8 vf1 = *(const bf16x8*)(Vc + rd*64 + (((quad+4) ^ sd)*8));
      o[t] = MFMA(pf0, vf0, o[t]);
      o[t] = MFMA(pf1, vf1, o[t]);
    }
    __syncthreads();   // prefetch landed + everyone done with cur
  }

  float inv[4];
#pragma unroll
  for (int r = 0; r < 4; ++r)
    inv[r] = (qm[r] && lacc[r] > 0.f) ? 1.0f / lacc[r] : 0.0f;

#pragma unroll
  for (int t = 0; t < 4; ++t)
#pragma unroll
    for (int r = 0; r < 4; ++r) {
      int row = b*SEQ + qrow0 + quad*4 + r;
      Ctx[(size_t)row*EMBED + h*HD + t*16 + l16] = (bf16)(o[t][r] * inv[r]);
    }
}

// ----------------------------------------------------------------------
extern "C" void kernel_launch(void* const* d_in, const int* in_sizes, int n_in,
                              void* d_out, int out_size, void* d_ws, size_t ws_size,
                              hipStream_t stream)
{
  const float* query = (const float*)d_in[0];
  const float* key   = (const float*)d_in[1];
  const float* value = (const float*)d_in[2];
  const int*   pm    = (const int*)d_in[3];
  const float* Wq = (const float*)d_in[4];
  const float* bq = (const float*)d_in[5];
  const float* Wk = (const float*)d_in[6];
  const float* bk = (const float*)d_in[7];
  const float* Wv = (const float*)d_in[8];
  const float* bv = (const float*)d_in[9];
  const float* Wo = (const float*)d_in[10];
  const float* bo = (const float*)d_in[11];
  float* out = (float*)d_out;

  const size_t SZ_X = (size_t)MROWS * EMBED;   // 4M elems
  const size_t SZ_W = (size_t)EMBED * EMBED;   // 1M elems

  bf16* p   = (bf16*)d_ws;
  bf16* Xq  = p; p += SZ_X;
  bf16* Xk  = p; p += SZ_X;
  bf16* Xv  = p; p += SZ_X;
  bf16* Wqb = p; p += SZ_W;
  bf16* Wkb = p; p += SZ_W;
  bf16* Wvb = p; p += SZ_W;
  bf16* Wob = p; p += SZ_W;
  bf16* Qp  = p; p += SZ_X;
  bf16* Kp  = p; p += SZ_X;
  bf16* VTg = p; p += SZ_X;   // V^T: [b][h][d][s]
  bf16* Ctx = p; p += SZ_X;

  // casts: 3x inputs (4M each), 4x weights (1M each)
  dim3 gx((unsigned)(SZ_X/8/256), 3);
  cast_multi<<<gx, 256, 0, stream>>>(query, key, value, query, Xq, Xk, Xv, Xq, (int)(SZ_X/8));
  dim3 gw((unsigned)(SZ_W/8/256), 4);
  cast_multi<<<gw, 256, 0, stream>>>(Wq, Wk, Wv, Wo, Wqb, Wkb, Wvb, Wob, (int)(SZ_W/8));

  dim3 gq(EMBED/BN, MROWS/BM, 3);   // (8, 32, 3)
  qkv_kernel<<<gq, 256, 0, stream>>>(Xq, Xk, Xv, Wqb, Wkb, Wvb, bq, bk, bv, Qp, Kp, VTg);

  dim3 ga(SEQ/64, NHEAD, BATCH);    // (32, 16, 2)
  attn_kernel<<<ga, 256, 0, stream>>>(Qp, Kp, VTg, pm, Ctx);

  dim3 gg(EMBED/BN, MROWS/BM);      // (8, 32)
  oproj_kernel<<<gg, 256, 0, stream>>>(Ctx, Wob, bo, out);
}

// Round 5
// 237.293 us; speedup vs baseline: 1.9512x; 1.0789x over previous
//
#include <hip/hip_runtime.h>
#include <cstdint>
#include <cstddef>

#define EMBED 1024
#define NHEAD 16
#define HD    64
#define BATCH 2
#define SEQ   2048
#define MROWS (BATCH*SEQ)   // 4096
#define QSCALE 0.1803368801111137f   // log2(e)/8

typedef __bf16 bf16;
typedef __bf16 bf16x8 __attribute__((ext_vector_type(8)));
typedef float  f32x4  __attribute__((ext_vector_type(4)));
typedef unsigned int u32;

#if __has_builtin(__builtin_amdgcn_exp2f)
#define EXP2(x) __builtin_amdgcn_exp2f(x)
#else
#define EXP2(x) exp2f(x)
#endif

typedef const u32 __attribute__((address_space(1)))* gp_t;
typedef u32 __attribute__((address_space(3)))* lp_t;

// async global->LDS, 16B/lane; LDS dest = wave-uniform base + lane*16
__device__ __forceinline__ void g2l16(const void* g, void* l) {
  __builtin_amdgcn_global_load_lds((gp_t)(uintptr_t)g, (lp_t)(u32)(uintptr_t)l, 16, 0, 0);
}

#define MFMA(a, b, c) __builtin_amdgcn_mfma_f32_16x16x32_bf16((a), (b), (c), 0, 0, 0)

// ---------------- fused casts fp32 -> bf16 ----------------------------
__global__ void cast_multi(const float* __restrict__ p0, const float* __restrict__ p1,
                           const float* __restrict__ p2, const float* __restrict__ p3,
                           bf16* o0, bf16* o1, bf16* o2, bf16* o3, int n8) {
  int z = blockIdx.y;
  const float* in = z==0?p0 : z==1?p1 : z==2?p2 : p3;
  bf16*       out = z==0?o0 : z==1?o1 : z==2?o2 : o3;
  int i = blockIdx.x * blockDim.x + threadIdx.x;
  if (i >= n8) return;
  const float4* p = (const float4*)in;
  float4 a = p[2*i], b = p[2*i+1];
  union { bf16 h[8]; uint4 u; } r;
  r.h[0] = (bf16)a.x; r.h[1] = (bf16)a.y; r.h[2] = (bf16)a.z; r.h[3] = (bf16)a.w;
  r.h[4] = (bf16)b.x; r.h[5] = (bf16)b.y; r.h[6] = (bf16)b.z; r.h[7] = (bf16)b.w;
  ((uint4*)out)[i] = r.u;
}

// ---------------- GEMM core 128x128: C = A @ W^T ----------------------
#define BM 128
#define BN 128
#define BK 32
#define NKI (EMBED/BK)   // 32

__device__ __forceinline__ void gemm_core(
    const bf16* __restrict__ A, const bf16* __restrict__ W,
    bf16* Al, bf16* Bl, f32x4 (&acc)[4][4])
{
  const int tid  = threadIdx.x;
  const int lane = tid & 63, wid = tid >> 6;
  const int quad = lane >> 4, l16 = lane & 15;
  const int wm = wid >> 1, wn = wid & 1;
  const int m0 = blockIdx.y * BM, n0 = blockIdx.x * BN;

  const int R = tid >> 2, Cc = tid & 3;
  const int gcol = (Cc ^ ((R >> 1) & 3)) * 8;          // swizzled source column
  const bf16* Ag = A + (size_t)(m0 + R) * EMBED + gcol;
  const bf16* Bg = W + (size_t)(n0 + R) * EMBED + gcol;
  bf16* AlW = Al + wid * 512;                          // wave's 1KB chunk
  bf16* BlW = Bl + wid * 512;

  g2l16(Ag, AlW);                      g2l16(Ag + (size_t)64*EMBED, AlW + 2048);
  g2l16(Bg, BlW);                      g2l16(Bg + (size_t)64*EMBED, BlW + 2048);
  __syncthreads();

  for (int ki = 0; ki < NKI; ++ki) {
    const int cur = ki & 1;
    if (ki + 1 < NKI) {
      const int nb = cur ^ 1;
      const int k0 = (ki + 1) * BK;
      g2l16(Ag + k0, AlW + nb*4096);
      g2l16(Ag + (size_t)64*EMBED + k0, AlW + nb*4096 + 2048);
      g2l16(Bg + k0, BlW + nb*4096);
      g2l16(Bg + (size_t)64*EMBED + k0, BlW + nb*4096 + 2048);
    }
    const bf16* Ac = Al + cur*4096;
    const bf16* Bc = Bl + cur*4096;
    bf16x8 af[4], bg[4];
#pragma unroll
    for (int i = 0; i < 4; ++i) {
      int ra = wm*64 + i*16 + l16;
      af[i] = *(const bf16x8*)(Ac + ra*32 + ((quad ^ ((ra>>1)&3))*8));
      int rb = wn*64 + i*16 + l16;
      bg[i] = *(const bf16x8*)(Bc + rb*32 + ((quad ^ ((rb>>1)&3))*8));
    }
#pragma unroll
    for (int i = 0; i < 4; ++i)
#pragma unroll
      for (int j = 0; j < 4; ++j)
        acc[i][j] = MFMA(af[i], bg[j], acc[i][j]);
    __syncthreads();
  }
}

// QKV fused: blockIdx.z selects {Q,K,V}. Q scaled by log2(e)/8.
// V written transposed: VT[b][h][d][s].
__global__ __launch_bounds__(256) void qkv_kernel(
    const bf16* __restrict__ Xq, const bf16* __restrict__ Xk, const bf16* __restrict__ Xv,
    const bf16* __restrict__ Wq, const bf16* __restrict__ Wk, const bf16* __restrict__ Wv,
    const float* __restrict__ bq, const float* __restrict__ bk, const float* __restrict__ bv,
    bf16* __restrict__ Qp, bf16* __restrict__ Kp, bf16* __restrict__ VTg)
{
  __shared__ bf16 Al[2*BM*BK];
  __shared__ bf16 Bl[2*BN*BK];
  const int z = blockIdx.z;
  const bf16* A = z==0 ? Xq : z==1 ? Xk : Xv;
  const bf16* W = z==0 ? Wq : z==1 ? Wk : Wv;
  const float* bias = z==0 ? bq : z==1 ? bk : bv;
  const float scale = (z==0) ? QSCALE : 1.0f;

  f32x4 acc[4][4] = {};
  gemm_core(A, W, Al, Bl, acc);

  const int lane = threadIdx.x & 63, wid = threadIdx.x >> 6;
  const int quad = lane >> 4, l16 = lane & 15;
  const int wm = wid >> 1, wn = wid & 1;
  const int m0 = blockIdx.y * BM, n0 = blockIdx.x * BN;

#pragma unroll
  for (int i = 0; i < 4; ++i) {
#pragma unroll
    for (int j = 0; j < 4; ++j) {
      int col = n0 + wn*64 + j*16 + l16;
      float bv2 = bias[col];
      if (z < 2) {
        bf16* outp = (z == 0) ? Qp : Kp;
#pragma unroll
        for (int r = 0; r < 4; ++r) {
          int row = m0 + wm*64 + i*16 + quad*4 + r;
          outp[(size_t)row*EMBED + col] = (bf16)((acc[i][j][r] + bv2) * scale);
        }
      } else {
        int row0 = m0 + wm*64 + i*16 + quad*4;
        int bb = row0 >> 11, ss = row0 & (SEQ-1);
        int hh = col >> 6, dd = col & (HD-1);
        union { bf16 h4[4]; uint2 u; } pk;
#pragma unroll
        for (int r = 0; r < 4; ++r) pk.h4[r] = (bf16)(acc[i][j][r] + bv2);
        *(uint2*)(VTg + (((size_t)bb*NHEAD + hh)*HD + dd)*SEQ + ss) = pk.u;
      }
    }
  }
}

// ---------------- O-projection: 128x64 tiles, fp32 out ----------------
// grid (EMBED/64, MROWS/128) = 512 blocks -> 2-3 blocks/CU.
__global__ __launch_bounds__(256) void oproj_kernel(
    const bf16* __restrict__ Ctx, const bf16* __restrict__ Wo,
    const float* __restrict__ bo, float* __restrict__ out)
{
  __shared__ bf16 Al[2*128*32];   // 2 x 8KB
  __shared__ bf16 Bl[2*64*32];    // 2 x 4KB
  const int tid  = threadIdx.x;
  const int lane = tid & 63, wid = tid >> 6;
  const int quad = lane >> 4, l16 = lane & 15;
  const int m0 = blockIdx.y * 128, n0 = blockIdx.x * 64;

  const int R = tid >> 2, Cc = tid & 3;
  const int gcol = (Cc ^ ((R >> 1) & 3)) * 8;
  const bf16* Ag = Ctx + (size_t)(m0 + R) * EMBED + gcol;
  const bf16* Bg = Wo  + (size_t)(n0 + R) * EMBED + gcol;   // R: 0..63 rows of B
  bf16* AlW = Al + wid * 512;
  bf16* BlW = Bl + wid * 512;

  g2l16(Ag, AlW);  g2l16(Ag + (size_t)64*EMBED, AlW + 2048);
  g2l16(Bg, BlW);
  __syncthreads();

  f32x4 acc[2][4] = {};
  for (int ki = 0; ki < NKI; ++ki) {
    const int cur = ki & 1;
    if (ki + 1 < NKI) {
      const int nb = cur ^ 1;
      const int k0 = (ki + 1) * BK;
      g2l16(Ag + k0, AlW + nb*4096);
      g2l16(Ag + (size_t)64*EMBED + k0, AlW + nb*4096 + 2048);
      g2l16(Bg + k0, BlW + nb*2048);
    }
    const bf16* Ac = Al + cur*4096;
    const bf16* Bc = Bl + cur*2048;
    bf16x8 af[2], bg[4];
#pragma unroll
    for (int u = 0; u < 2; ++u) {
      int ra = wid*32 + u*16 + l16;
      af[u] = *(const bf16x8*)(Ac + ra*32 + ((quad ^ ((ra>>1)&3))*8));
    }
#pragma unroll
    for (int j = 0; j < 4; ++j) {
      int rb = j*16 + l16;
      bg[j] = *(const bf16x8*)(Bc + rb*32 + ((quad ^ ((rb>>1)&3))*8));
    }
#pragma unroll
    for (int u = 0; u < 2; ++u)
#pragma unroll
      for (int j = 0; j < 4; ++j)
        acc[u][j] = MFMA(af[u], bg[j], acc[u][j]);
    __syncthreads();
  }

#pragma unroll
  for (int u = 0; u < 2; ++u)
#pragma unroll
    for (int j = 0; j < 4; ++j) {
      int col = n0 + j*16 + l16;
      float bv = bo[col];
#pragma unroll
      for (int r = 0; r < 4; ++r) {
        int row = m0 + wid*32 + u*16 + quad*4 + r;
        out[(size_t)row*EMBED + col] = (acc[u][j][r] + bv);
      }
    }
}

// ---------------- flash attention, no-max softmax ---------------------
// 128 q-rows/block, 4 waves x 32 rows (2 rowgroups); 64-key tiles;
// K/V frags loaded once per tile, reused across rowgroups (halves LDS reads).
// Double-buffered K/V via global_load_lds, chunk-swizzled; 1 barrier/tile.
#define NT  (SEQ/64)
#define PST 68   // P row stride: quads tile banks at offsets 0/8/16/24 -> 2-way max

__global__ __launch_bounds__(256, 3) void attn_kernel(
    const bf16* __restrict__ Qp, const bf16* __restrict__ Kp, const bf16* __restrict__ VT,
    const int* __restrict__ pmask, bf16* __restrict__ Ctx)
{
  __shared__ bf16 Kt[2][64*64];    // 16 KB
  __shared__ bf16 Vt[2][64*64];    // 16 KB
  __shared__ bf16 Pl[4][32*PST];   // 17.4 KB

  const int qt = blockIdx.x, h = blockIdx.y, b = blockIdx.z;
  const int tid = threadIdx.x, lane = tid & 63, wid = tid >> 6;
  const int quad = lane >> 4, l16 = lane & 15;
  const int qrow0 = qt*128 + wid*32;

  bf16x8 qf[2][2];
#pragma unroll
  for (int u = 0; u < 2; ++u) {
    const size_t qoff = (size_t)(b*SEQ + qrow0 + u*16 + l16)*EMBED + h*HD;
    qf[u][0] = *(const bf16x8*)(Qp + qoff + quad*8);
    qf[u][1] = *(const bf16x8*)(Qp + qoff + 32 + quad*8);
  }

  int qm[2][4];
#pragma unroll
  for (int u = 0; u < 2; ++u)
#pragma unroll
    for (int r = 0; r < 4; ++r) qm[u][r] = pmask[b*SEQ + qrow0 + u*16 + quad*4 + r];

  bf16 onev = (bf16)1.0f;
  bf16x8 ones = {onev, onev, onev, onev, onev, onev, onev, onev};

  const bf16* Kg  = Kp + (size_t)b*SEQ*EMBED + h*HD;
  const bf16* VTg = VT + (size_t)(b*NHEAD + h)*HD*SEQ;

  const int R = tid >> 3;                 // 0..31 (key idx for K, dim for V)
  const int Cc = tid & 7;
  const int scol = (Cc ^ (R & 7)) * 8;    // swizzled source column

  f32x4 o[2][4] = {};
  f32x4 lacc[2] = {};

#define STAGE(kt, buf) do {                                              \
    const bf16* kg = Kg + (size_t)((kt)*64 + R)*EMBED + scol;            \
    const bf16* vg = VTg + (size_t)R*SEQ + (kt)*64 + scol;               \
    bf16* kl = &Kt[buf][0] + wid*512;                                    \
    bf16* vl = &Vt[buf][0] + wid*512;                                    \
    g2l16(kg, kl);  g2l16(kg + (size_t)32*EMBED, kl + 2048);             \
    g2l16(vg, vl);  g2l16(vg + (size_t)32*SEQ,   vl + 2048);             \
  } while (0)

  STAGE(0, 0);
  __syncthreads();

  for (int kt = 0; kt < NT; ++kt) {
    const int cur = kt & 1;
    if (kt + 1 < NT) STAGE(kt + 1, cur ^ 1);   // async, lands by next barrier
    const bf16* Kc = &Kt[cur][0];
    const bf16* Vc = &Vt[cur][0];

    // QK^T + exp2 + P store; K frags shared across both rowgroups
#pragma unroll
    for (int g = 0; g < 4; ++g) {
      int ra = g*16 + l16, sa = ra & 7;
      bf16x8 kfa = *(const bf16x8*)(Kc + ra*64 + ((quad     ^ sa)*8));
      bf16x8 kfb = *(const bf16x8*)(Kc + ra*64 + (((quad+4) ^ sa)*8));
      int km = pmask[b*SEQ + kt*64 + g*16 + l16];
#pragma unroll
      for (int u = 0; u < 2; ++u) {
        f32x4 sg = {};
        sg = MFMA(qf[u][0], kfa, sg);
        sg = MFMA(qf[u][1], kfb, sg);
#pragma unroll
        for (int r = 0; r < 4; ++r) {
          float pv = km ? EXP2(sg[r]) : 0.0f;
          Pl[wid][(u*16 + quad*4 + r)*PST + g*16 + l16] = (bf16)pv;
        }
      }
    }

    // wave-private P: same-wave DS ordering, no barrier needed
    bf16x8 pf[2][2];
#pragma unroll
    for (int u = 0; u < 2; ++u) {
      pf[u][0] = *(const bf16x8*)(&Pl[wid][(u*16 + l16)*PST + quad*8]);
      pf[u][1] = *(const bf16x8*)(&Pl[wid][(u*16 + l16)*PST + 32 + quad*8]);
      lacc[u] = MFMA(pf[u][0], ones, lacc[u]);
      lacc[u] = MFMA(pf[u][1], ones, lacc[u]);
    }
    // PV: V frags shared across both rowgroups
#pragma unroll
    for (int t = 0; t < 4; ++t) {
      int rd = t*16 + l16, sd = rd & 7;
      bf16x8 vf0 = *(const bf16x8*)(Vc + rd*64 + ((quad     ^ sd)*8));
      bf16x8 vf1 = *(const bf16x8*)(Vc + rd*64 + (((quad+4) ^ sd)*8));
#pragma unroll
      for (int u = 0; u < 2; ++u) {
        o[u][t] = MFMA(pf[u][0], vf0, o[u][t]);
        o[u][t] = MFMA(pf[u][1], vf1, o[u][t]);
      }
    }
    __syncthreads();   // prefetch landed + everyone done with cur
  }

#pragma unroll
  for (int u = 0; u < 2; ++u) {
    float inv[4];
#pragma unroll
    for (int r = 0; r < 4; ++r)
      inv[r] = (qm[u][r] && lacc[u][r] > 0.f) ? 1.0f / lacc[u][r] : 0.0f;
#pragma unroll
    for (int t = 0; t < 4; ++t)
#pragma unroll
      for (int r = 0; r < 4; ++r) {
        int row = b*SEQ + qrow0 + u*16 + quad*4 + r;
        Ctx[(size_t)row*EMBED + h*HD + t*16 + l16] = (bf16)(o[u][t][r] * inv[r]);
      }
  }
}

// ----------------------------------------------------------------------
extern "C" void kernel_launch(void* const* d_in, const int* in_sizes, int n_in,
                              void* d_out, int out_size, void* d_ws, size_t ws_size,
                              hipStream_t stream)
{
  const float* query = (const float*)d_in[0];
  const float* key   = (const float*)d_in[1];
  const float* value = (const float*)d_in[2];
  const int*   pm    = (const int*)d_in[3];
  const float* Wq = (const float*)d_in[4];
  const float* bq = (const float*)d_in[5];
  const float* Wk = (const float*)d_in[6];
  const float* bk = (const float*)d_in[7];
  const float* Wv = (const float*)d_in[8];
  const float* bv = (const float*)d_in[9];
  const float* Wo = (const float*)d_in[10];
  const float* bo = (const float*)d_in[11];
  float* out = (float*)d_out;

  const size_t SZ_X = (size_t)MROWS * EMBED;   // 4M elems
  const size_t SZ_W = (size_t)EMBED * EMBED;   // 1M elems

  bf16* p   = (bf16*)d_ws;
  bf16* Xq  = p; p += SZ_X;
  bf16* Xk  = p; p += SZ_X;
  bf16* Xv  = p; p += SZ_X;
  bf16* Wqb = p; p += SZ_W;
  bf16* Wkb = p; p += SZ_W;
  bf16* Wvb = p; p += SZ_W;
  bf16* Wob = p; p += SZ_W;
  bf16* Qp  = p; p += SZ_X;
  bf16* Kp  = p; p += SZ_X;
  bf16* VTg = p; p += SZ_X;   // V^T: [b][h][d][s]
  bf16* Ctx = p; p += SZ_X;

  dim3 gx((unsigned)(SZ_X/8/256), 3);
  cast_multi<<<gx, 256, 0, stream>>>(query, key, value, query, Xq, Xk, Xv, Xq, (int)(SZ_X/8));
  dim3 gw((unsigned)(SZ_W/8/256), 4);
  cast_multi<<<gw, 256, 0, stream>>>(Wq, Wk, Wv, Wo, Wqb, Wkb, Wvb, Wob, (int)(SZ_W/8));

  dim3 gq(EMBED/BN, MROWS/BM, 3);   // (8, 32, 3)
  qkv_kernel<<<gq, 256, 0, stream>>>(Xq, Xk, Xv, Wqb, Wkb, Wvb, bq, bk, bv, Qp, Kp, VTg);

  dim3 ga(SEQ/128, NHEAD, BATCH);   // (16, 16, 2) = 512 blocks
  attn_kernel<<<ga, 256, 0, stream>>>(Qp, Kp, VTg, pm, Ctx);

  dim3 gg(EMBED/64, MROWS/128);     // (16, 32) = 512 blocks
  oproj_kernel<<<gg, 256, 0, stream>>>(Ctx, Wob, bo, out);
}

// Round 6
// 234.677 us; speedup vs baseline: 1.9729x; 1.0112x over previous
//
#include <hip/hip_runtime.h>
#include <cstdint>
#include <cstddef>

#define EMBED 1024
#define NHEAD 16
#define HD    64
#define BATCH 2
#define SEQ   2048
#define MROWS (BATCH*SEQ)   // 4096
#define QSCALE 0.1803368801111137f   // log2(e)/8

typedef __bf16 bf16;
typedef __bf16 bf16x8 __attribute__((ext_vector_type(8)));
typedef float  f32x4  __attribute__((ext_vector_type(4)));
typedef unsigned int u32;

#if __has_builtin(__builtin_amdgcn_exp2f)
#define EXP2(x) __builtin_amdgcn_exp2f(x)
#else
#define EXP2(x) exp2f(x)
#endif

typedef const u32 __attribute__((address_space(1)))* gp_t;
typedef u32 __attribute__((address_space(3)))* lp_t;

// async global->LDS, 16B/lane; LDS dest = wave-uniform base + lane*16
__device__ __forceinline__ void g2l16(const void* g, void* l) {
  __builtin_amdgcn_global_load_lds((gp_t)(uintptr_t)g, (lp_t)(u32)(uintptr_t)l, 16, 0, 0);
}

#define MFMA(a, b, c) __builtin_amdgcn_mfma_f32_16x16x32_bf16((a), (b), (c), 0, 0, 0)

// ---------------- all casts fp32 -> bf16, one dispatch ----------------
#define SZX8 ((MROWS*EMBED)/8)   // 524288
#define SZW8 ((EMBED*EMBED)/8)   // 131072

__global__ void cast_all(const float* __restrict__ q, const float* __restrict__ k,
                         const float* __restrict__ v, const float* __restrict__ wq,
                         const float* __restrict__ wk, const float* __restrict__ wv,
                         const float* __restrict__ wo,
                         bf16* xq, bf16* xk, bf16* xv,
                         bf16* wqb, bf16* wkb, bf16* wvb, bf16* wob) {
  int z = blockIdx.y;
  const float* in; bf16* out;
  switch (z) {
    case 0: in = q;  out = xq;  break;
    case 1: in = k;  out = xk;  break;
    case 2: in = v;  out = xv;  break;
    case 3: in = wq; out = wqb; break;
    case 4: in = wk; out = wkb; break;
    case 5: in = wv; out = wvb; break;
    default: in = wo; out = wob; break;
  }
  int n8 = (z < 3) ? SZX8 : SZW8;
  int i = blockIdx.x * blockDim.x + threadIdx.x;
  if (i >= n8) return;
  const float4* p = (const float4*)in;
  float4 a = p[2*i], b = p[2*i+1];
  union { bf16 h[8]; uint4 u; } r;
  r.h[0] = (bf16)a.x; r.h[1] = (bf16)a.y; r.h[2] = (bf16)a.z; r.h[3] = (bf16)a.w;
  r.h[4] = (bf16)b.x; r.h[5] = (bf16)b.y; r.h[6] = (bf16)b.z; r.h[7] = (bf16)b.w;
  ((uint4*)out)[i] = r.u;
}

// ---------------- GEMM core 128x128: C = A @ W^T ----------------------
#define BM 128
#define BN 128
#define BK 32
#define NKI (EMBED/BK)   // 32

__device__ __forceinline__ void gemm_core(
    const bf16* __restrict__ A, const bf16* __restrict__ W,
    bf16* Al, bf16* Bl, f32x4 (&acc)[4][4])
{
  const int tid  = threadIdx.x;
  const int lane = tid & 63, wid = tid >> 6;
  const int quad = lane >> 4, l16 = lane & 15;
  const int wm = wid >> 1, wn = wid & 1;
  const int m0 = blockIdx.y * BM, n0 = blockIdx.x * BN;

  const int R = tid >> 2, Cc = tid & 3;
  const int gcol = (Cc ^ ((R >> 1) & 3)) * 8;          // swizzled source column
  const bf16* Ag = A + (size_t)(m0 + R) * EMBED + gcol;
  const bf16* Bg = W + (size_t)(n0 + R) * EMBED + gcol;
  bf16* AlW = Al + wid * 512;                          // wave's 1KB chunk
  bf16* BlW = Bl + wid * 512;

  g2l16(Ag, AlW);                      g2l16(Ag + (size_t)64*EMBED, AlW + 2048);
  g2l16(Bg, BlW);                      g2l16(Bg + (size_t)64*EMBED, BlW + 2048);
  __syncthreads();

  for (int ki = 0; ki < NKI; ++ki) {
    const int cur = ki & 1;
    if (ki + 1 < NKI) {
      const int nb = cur ^ 1;
      const int k0 = (ki + 1) * BK;
      g2l16(Ag + k0, AlW + nb*4096);
      g2l16(Ag + (size_t)64*EMBED + k0, AlW + nb*4096 + 2048);
      g2l16(Bg + k0, BlW + nb*4096);
      g2l16(Bg + (size_t)64*EMBED + k0, BlW + nb*4096 + 2048);
    }
    const bf16* Ac = Al + cur*4096;
    const bf16* Bc = Bl + cur*4096;
    bf16x8 af[4], bg[4];
#pragma unroll
    for (int i = 0; i < 4; ++i) {
      int ra = wm*64 + i*16 + l16;
      af[i] = *(const bf16x8*)(Ac + ra*32 + ((quad ^ ((ra>>1)&3))*8));
      int rb = wn*64 + i*16 + l16;
      bg[i] = *(const bf16x8*)(Bc + rb*32 + ((quad ^ ((rb>>1)&3))*8));
    }
#pragma unroll
    for (int i = 0; i < 4; ++i)
#pragma unroll
      for (int j = 0; j < 4; ++j)
        acc[i][j] = MFMA(af[i], bg[j], acc[i][j]);
    __syncthreads();
  }
}

// QKV fused: blockIdx.z selects {Q,K,V}. Q scaled by log2(e)/8.
// V written transposed AND pi-permuted per 64-token tile:
// global pos = tile*64 + pi(local), pi(x) = (x&15)*4 + (x>>4).
__global__ __launch_bounds__(256) void qkv_kernel(
    const bf16* __restrict__ Xq, const bf16* __restrict__ Xk, const bf16* __restrict__ Xv,
    const bf16* __restrict__ Wq, const bf16* __restrict__ Wk, const bf16* __restrict__ Wv,
    const float* __restrict__ bq, const float* __restrict__ bk, const float* __restrict__ bv,
    bf16* __restrict__ Qp, bf16* __restrict__ Kp, bf16* __restrict__ VTg)
{
  __shared__ bf16 Al[2*BM*BK];
  __shared__ bf16 Bl[2*BN*BK];
  const int z = blockIdx.z;
  const bf16* A = z==0 ? Xq : z==1 ? Xk : Xv;
  const bf16* W = z==0 ? Wq : z==1 ? Wk : Wv;
  const float* bias = z==0 ? bq : z==1 ? bk : bv;
  const float scale = (z==0) ? QSCALE : 1.0f;

  f32x4 acc[4][4] = {};
  gemm_core(A, W, Al, Bl, acc);

  const int lane = threadIdx.x & 63, wid = threadIdx.x >> 6;
  const int quad = lane >> 4, l16 = lane & 15;
  const int wm = wid >> 1, wn = wid & 1;
  const int m0 = blockIdx.y * BM, n0 = blockIdx.x * BN;

#pragma unroll
  for (int i = 0; i < 4; ++i) {
#pragma unroll
    for (int j = 0; j < 4; ++j) {
      int col = n0 + wn*64 + j*16 + l16;
      float bv2 = bias[col];
      if (z < 2) {
        bf16* outp = (z == 0) ? Qp : Kp;
#pragma unroll
        for (int r = 0; r < 4; ++r) {
          int row = m0 + wm*64 + i*16 + quad*4 + r;
          outp[(size_t)row*EMBED + col] = (bf16)((acc[i][j][r] + bv2) * scale);
        }
      } else {
        int row0 = m0 + wm*64 + i*16 + quad*4;
        int bb = row0 >> 11, ss0 = row0 & (SEQ-1);
        int hh = col >> 6, dd = col & (HD-1);
        const size_t base = (((size_t)bb*NHEAD + hh)*HD + dd)*SEQ;
#pragma unroll
        for (int r = 0; r < 4; ++r) {
          int s = ss0 + r;
          int tile = s >> 6, loc = s & 63;
          int p = ((loc & 15) << 2) | (loc >> 4);   // pi(loc)
          VTg[base + tile*64 + p] = (bf16)(acc[i][j][r] + bv2);
        }
      }
    }
  }
}

// ---------------- O-projection: 128x64 tiles, fp32 out ----------------
__global__ __launch_bounds__(256) void oproj_kernel(
    const bf16* __restrict__ Ctx, const bf16* __restrict__ Wo,
    const float* __restrict__ bo, float* __restrict__ out)
{
  __shared__ bf16 Al[2*128*32];   // 2 x 8KB
  __shared__ bf16 Bl[2*64*32];    // 2 x 4KB
  const int tid  = threadIdx.x;
  const int lane = tid & 63, wid = tid >> 6;
  const int quad = lane >> 4, l16 = lane & 15;
  const int m0 = blockIdx.y * 128, n0 = blockIdx.x * 64;

  const int R = tid >> 2, Cc = tid & 3;
  const int gcol = (Cc ^ ((R >> 1) & 3)) * 8;
  const bf16* Ag = Ctx + (size_t)(m0 + R) * EMBED + gcol;
  const bf16* Bg = Wo  + (size_t)(n0 + R) * EMBED + gcol;
  bf16* AlW = Al + wid * 512;
  bf16* BlW = Bl + wid * 512;

  g2l16(Ag, AlW);  g2l16(Ag + (size_t)64*EMBED, AlW + 2048);
  g2l16(Bg, BlW);
  __syncthreads();

  f32x4 acc[2][4] = {};
  for (int ki = 0; ki < NKI; ++ki) {
    const int cur = ki & 1;
    if (ki + 1 < NKI) {
      const int nb = cur ^ 1;
      const int k0 = (ki + 1) * BK;
      g2l16(Ag + k0, AlW + nb*4096);
      g2l16(Ag + (size_t)64*EMBED + k0, AlW + nb*4096 + 2048);
      g2l16(Bg + k0, BlW + nb*2048);
    }
    const bf16* Ac = Al + cur*4096;
    const bf16* Bc = Bl + cur*2048;
    bf16x8 af[2], bg[4];
#pragma unroll
    for (int u = 0; u < 2; ++u) {
      int ra = wid*32 + u*16 + l16;
      af[u] = *(const bf16x8*)(Ac + ra*32 + ((quad ^ ((ra>>1)&3))*8));
    }
#pragma unroll
    for (int j = 0; j < 4; ++j) {
      int rb = j*16 + l16;
      bg[j] = *(const bf16x8*)(Bc + rb*32 + ((quad ^ ((rb>>1)&3))*8));
    }
#pragma unroll
    for (int u = 0; u < 2; ++u)
#pragma unroll
      for (int j = 0; j < 4; ++j)
        acc[u][j] = MFMA(af[u], bg[j], acc[u][j]);
    __syncthreads();
  }

#pragma unroll
  for (int u = 0; u < 2; ++u)
#pragma unroll
    for (int j = 0; j < 4; ++j) {
      int col = n0 + j*16 + l16;
      float bv = bo[col];
#pragma unroll
      for (int r = 0; r < 4; ++r) {
        int row = m0 + wid*32 + u*16 + quad*4 + r;
        out[(size_t)row*EMBED + col] = (acc[u][j][r] + bv);
      }
    }
}

// ---------------- flash attention, no-max softmax ---------------------
// 128 q-rows/block, 4 waves x 32 rows (2 rowgroups); 64-key tiles.
// P written pi-packed: position p = l16*4 + g -> one ds_write_b64 per
// (u,r) instead of 4 scalar b16 stores. V^T is pi-ordered in global
// memory (written that way by qkv), so PV contracts matching key orders.
#define NT  (SEQ/64)
#define PST 72   // P row stride: 144 B rows -> 16B-aligned b128 reads, 2-way max banks

__global__ __launch_bounds__(256, 3) void attn_kernel(
    const bf16* __restrict__ Qp, const bf16* __restrict__ Kp, const bf16* __restrict__ VT,
    const int* __restrict__ pmask, bf16* __restrict__ Ctx)
{
  __shared__ bf16 Kt[2][64*64];    // 16 KB
  __shared__ bf16 Vt[2][64*64];    // 16 KB
  __shared__ bf16 Pl[4][32*PST];   // 18.4 KB

  const int qt = blockIdx.x, h = blockIdx.y, b = blockIdx.z;
  const int tid = threadIdx.x, lane = tid & 63, wid = tid >> 6;
  const int quad = lane >> 4, l16 = lane & 15;
  const int qrow0 = qt*128 + wid*32;

  bf16x8 qf[2][2];
#pragma unroll
  for (int u = 0; u < 2; ++u) {
    const size_t qoff = (size_t)(b*SEQ + qrow0 + u*16 + l16)*EMBED + h*HD;
    qf[u][0] = *(const bf16x8*)(Qp + qoff + quad*8);
    qf[u][1] = *(const bf16x8*)(Qp + qoff + 32 + quad*8);
  }

  int qm[2][4];
#pragma unroll
  for (int u = 0; u < 2; ++u)
#pragma unroll
    for (int r = 0; r < 4; ++r) qm[u][r] = pmask[b*SEQ + qrow0 + u*16 + quad*4 + r];

  bf16 onev = (bf16)1.0f;
  bf16x8 ones = {onev, onev, onev, onev, onev, onev, onev, onev};

  const bf16* Kg  = Kp + (size_t)b*SEQ*EMBED + h*HD;
  const bf16* VTg = VT + (size_t)(b*NHEAD + h)*HD*SEQ;

  const int R = tid >> 3;                 // 0..31 (key idx for K, dim for V)
  const int Cc = tid & 7;
  const int scol = (Cc ^ (R & 7)) * 8;    // swizzled source column

  f32x4 o[2][4] = {};
  f32x4 lacc[2] = {};

#define STAGE(kt, buf) do {                                              \
    const bf16* kg = Kg + (size_t)((kt)*64 + R)*EMBED + scol;            \
    const bf16* vg = VTg + (size_t)R*SEQ + (kt)*64 + scol;               \
    bf16* kl = &Kt[buf][0] + wid*512;                                    \
    bf16* vl = &Vt[buf][0] + wid*512;                                    \
    g2l16(kg, kl);  g2l16(kg + (size_t)32*EMBED, kl + 2048);             \
    g2l16(vg, vl);  g2l16(vg + (size_t)32*SEQ,   vl + 2048);             \
  } while (0)

  STAGE(0, 0);
  __syncthreads();

  for (int kt = 0; kt < NT; ++kt) {
    const int cur = kt & 1;
    if (kt + 1 < NT) STAGE(kt + 1, cur ^ 1);   // async, lands by next barrier
    const bf16* Kc = &Kt[cur][0];
    const bf16* Vc = &Vt[cur][0];

    // QK^T + mask + exp2, all 4 key groups; K frags shared across rowgroups
    f32x4 sg[2][4];
#pragma unroll
    for (int g = 0; g < 4; ++g) {
      int ra = g*16 + l16, sa = ra & 7;
      bf16x8 kfa = *(const bf16x8*)(Kc + ra*64 + ((quad     ^ sa)*8));
      bf16x8 kfb = *(const bf16x8*)(Kc + ra*64 + (((quad+4) ^ sa)*8));
      int km = pmask[b*SEQ + kt*64 + g*16 + l16];
#pragma unroll
      for (int u = 0; u < 2; ++u) {
        f32x4 s = {};
        s = MFMA(qf[u][0], kfa, s);
        s = MFMA(qf[u][1], kfb, s);
#pragma unroll
        for (int r = 0; r < 4; ++r) sg[u][g][r] = km ? EXP2(s[r]) : 0.0f;
      }
    }

    // pi-packed P store: position l16*4+g -> one b64 per (u,r)
#pragma unroll
    for (int u = 0; u < 2; ++u)
#pragma unroll
      for (int r = 0; r < 4; ++r) {
        union { bf16 h[4]; uint2 uu; } pk;
#pragma unroll
        for (int g = 0; g < 4; ++g) pk.h[g] = (bf16)sg[u][g][r];
        *(uint2*)(&Pl[wid][(u*16 + quad*4 + r)*PST + l16*4]) = pk.uu;
      }

    // wave-private P: same-wave DS ordering, no barrier needed
    bf16x8 pf[2][2];
#pragma unroll
    for (int u = 0; u < 2; ++u) {
      pf[u][0] = *(const bf16x8*)(&Pl[wid][(u*16 + l16)*PST + quad*8]);
      pf[u][1] = *(const bf16x8*)(&Pl[wid][(u*16 + l16)*PST + 32 + quad*8]);
      lacc[u] = MFMA(pf[u][0], ones, lacc[u]);
      lacc[u] = MFMA(pf[u][1], ones, lacc[u]);
    }
    // PV: V frags (pi-ordered, matching P) shared across both rowgroups
#pragma unroll
    for (int t = 0; t < 4; ++t) {
      int rd = t*16 + l16, sd = rd & 7;
      bf16x8 vf0 = *(const bf16x8*)(Vc + rd*64 + ((quad     ^ sd)*8));
      bf16x8 vf1 = *(const bf16x8*)(Vc + rd*64 + (((quad+4) ^ sd)*8));
#pragma unroll
      for (int u = 0; u < 2; ++u) {
        o[u][t] = MFMA(pf[u][0], vf0, o[u][t]);
        o[u][t] = MFMA(pf[u][1], vf1, o[u][t]);
      }
    }
    __syncthreads();   // prefetch landed + everyone done with cur
  }

#pragma unroll
  for (int u = 0; u < 2; ++u) {
    float inv[4];
#pragma unroll
    for (int r = 0; r < 4; ++r)
      inv[r] = (qm[u][r] && lacc[u][r] > 0.f) ? 1.0f / lacc[u][r] : 0.0f;
#pragma unroll
    for (int t = 0; t < 4; ++t)
#pragma unroll
      for (int r = 0; r < 4; ++r) {
        int row = b*SEQ + qrow0 + u*16 + quad*4 + r;
        Ctx[(size_t)row*EMBED + h*HD + t*16 + l16] = (bf16)(o[u][t][r] * inv[r]);
      }
  }
}

// ----------------------------------------------------------------------
extern "C" void kernel_launch(void* const* d_in, const int* in_sizes, int n_in,
                              void* d_out, int out_size, void* d_ws, size_t ws_size,
                              hipStream_t stream)
{
  const float* query = (const float*)d_in[0];
  const float* key   = (const float*)d_in[1];
  const float* value = (const float*)d_in[2];
  const int*   pm    = (const int*)d_in[3];
  const float* Wq = (const float*)d_in[4];
  const float* bq = (const float*)d_in[5];
  const float* Wk = (const float*)d_in[6];
  const float* bk = (const float*)d_in[7];
  const float* Wv = (const float*)d_in[8];
  const float* bv = (const float*)d_in[9];
  const float* Wo = (const float*)d_in[10];
  const float* bo = (const float*)d_in[11];
  float* out = (float*)d_out;

  const size_t SZ_X = (size_t)MROWS * EMBED;   // 4M elems
  const size_t SZ_W = (size_t)EMBED * EMBED;   // 1M elems

  bf16* p   = (bf16*)d_ws;
  bf16* Xq  = p; p += SZ_X;
  bf16* Xk  = p; p += SZ_X;
  bf16* Xv  = p; p += SZ_X;
  bf16* Wqb = p; p += SZ_W;
  bf16* Wkb = p; p += SZ_W;
  bf16* Wvb = p; p += SZ_W;
  bf16* Wob = p; p += SZ_W;
  bf16* Qp  = p; p += SZ_X;
  bf16* Kp  = p; p += SZ_X;
  bf16* VTg = p; p += SZ_X;   // V^T: [b][h][d][pi-ordered s]
  bf16* Ctx = p; p += SZ_X;

  dim3 gc((unsigned)(SZX8/256), 7);   // one dispatch for all 7 casts
  cast_all<<<gc, 256, 0, stream>>>(query, key, value, Wq, Wk, Wv, Wo,
                                   Xq, Xk, Xv, Wqb, Wkb, Wvb, Wob);

  dim3 gq(EMBED/BN, MROWS/BM, 3);   // (8, 32, 3)
  qkv_kernel<<<gq, 256, 0, stream>>>(Xq, Xk, Xv, Wqb, Wkb, Wvb, bq, bk, bv, Qp, Kp, VTg);

  dim3 ga(SEQ/128, NHEAD, BATCH);   // (16, 16, 2) = 512 blocks
  attn_kernel<<<ga, 256, 0, stream>>>(Qp, Kp, VTg, pm, Ctx);

  dim3 gg(EMBED/64, MROWS/128);     // (16, 32) = 512 blocks
  oproj_kernel<<<gg, 256, 0, stream>>>(Ctx, Wob, bo, out);
}